// Round 1
// baseline (326.246 us; speedup 1.0000x reference)
//
#include <hip/hip_runtime.h>

typedef short short8 __attribute__((ext_vector_type(8)));
typedef float f32x4 __attribute__((ext_vector_type(4)));

__device__ __forceinline__ unsigned short f2bf(float f){
  union { float f; unsigned int u; } x; x.f = f;
  unsigned int r = x.u + 0x7fffu + ((x.u >> 16) & 1u);
  return (unsigned short)(r >> 16);
}

__device__ __forceinline__ void gload_lds16(const void* g, void* l){
  __builtin_amdgcn_global_load_lds(
      (const __attribute__((address_space(1))) void*)g,
      (__attribute__((address_space(3))) void*)l, 16, 0, 0);
}

// ---------------- cast fp32 -> bf16 ----------------
__global__ __launch_bounds__(256) void cast_f32_bf16(const float* __restrict__ in,
                                                     unsigned short* __restrict__ out, int n4){
  int i = blockIdx.x * blockDim.x + threadIdx.x;
  const int stride = gridDim.x * blockDim.x;
  for (; i < n4; i += stride){
    float4 v = ((const float4*)in)[i];
    ushort4 o;
    o.x = f2bf(v.x); o.y = f2bf(v.y); o.z = f2bf(v.z); o.w = f2bf(v.w);
    ((ushort4*)out)[i] = o;
  }
}

// ---------------- transpose W[K][N] f32 -> WT[N][K] bf16 ----------------
__global__ __launch_bounds__(256) void transpose_to_bf16(const float* __restrict__ W,
                                                         unsigned short* __restrict__ WT,
                                                         int K, int N){
  __shared__ float tile[64][68];
  const int n0 = blockIdx.x * 64, k0 = blockIdx.y * 64;
  const int t = threadIdx.x;
  const int qn = (t & 15) * 4;
  #pragma unroll
  for (int i = 0; i < 4; ++i){
    const int kk = (t >> 4) + i * 16;
    float4 v = *(const float4*)&W[(size_t)(k0 + kk) * N + n0 + qn];
    tile[kk][qn + 0] = v.x; tile[kk][qn + 1] = v.y;
    tile[kk][qn + 2] = v.z; tile[kk][qn + 3] = v.w;
  }
  __syncthreads();
  const int qk = (t & 15) * 4;
  #pragma unroll
  for (int i = 0; i < 4; ++i){
    const int nn = (t >> 4) + i * 16;
    ushort4 o;
    o.x = f2bf(tile[qk + 0][nn]); o.y = f2bf(tile[qk + 1][nn]);
    o.z = f2bf(tile[qk + 2][nn]); o.w = f2bf(tile[qk + 3][nn]);
    *(ushort4*)&WT[(size_t)(n0 + nn) * K + k0 + qk] = o;
  }
}

// ---------------- GEMM: A[8192][768]bf16 x Bt[N][768]bf16 ----------------
// EPI 0: scatter to q/k/v [3][B=4][H=12][S=2048][64] bf16 + bias
// EPI 1: out fp32 [8192][768] + bias
template<int EPI>
__global__ __launch_bounds__(256) void gemm_bf16(const unsigned short* __restrict__ A,
                                                 const unsigned short* __restrict__ Bt,
                                                 const float* __restrict__ bias,
                                                 void* __restrict__ outp){
  __shared__ unsigned short As[2][128 * 32];
  __shared__ unsigned short Bs[2][128 * 32];
  const int tid = threadIdx.x;
  const int wave = tid >> 6, lane = tid & 63;
  const int g = lane >> 4, l15 = lane & 15;
  const int wr = wave >> 1, wc = wave & 1;
  const int m0 = blockIdx.y * 128, n0 = blockIdx.x * 128;

  f32x4 acc[4][4] = {};

  auto stage = [&](int bi, int kt){
    const int k0 = kt * 32;
    #pragma unroll
    for (int c = 0; c < 2; ++c){
      const int z = c * 4096 + tid * 16;
      const int r = z >> 6;
      const int ys = (z & 63) ^ ((r & 3) << 4);
      gload_lds16((const char*)A + ((size_t)(m0 + r) * 768 + k0) * 2 + ys,
                  (char*)&As[bi][0] + c * 4096 + wave * 1024);
      gload_lds16((const char*)Bt + ((size_t)(n0 + r) * 768 + k0) * 2 + ys,
                  (char*)&Bs[bi][0] + c * 4096 + wave * 1024);
    }
  };

  stage(0, 0);
  for (int kt = 0; kt < 24; ++kt){
    __syncthreads();
    if (kt + 1 < 24) stage((kt + 1) & 1, kt + 1);
    const char* Ab = (const char*)&As[kt & 1][0];
    const char* Bb = (const char*)&Bs[kt & 1][0];
    short8 a[4], b[4];
    #pragma unroll
    for (int mt = 0; mt < 4; ++mt){
      const int row = wr * 64 + mt * 16 + l15;
      a[mt] = *(const short8*)(Ab + row * 64 + ((g * 16) ^ ((row & 3) << 4)));
    }
    #pragma unroll
    for (int nt = 0; nt < 4; ++nt){
      const int row = wc * 64 + nt * 16 + l15;
      b[nt] = *(const short8*)(Bb + row * 64 + ((g * 16) ^ ((row & 3) << 4)));
    }
    #pragma unroll
    for (int mt = 0; mt < 4; ++mt)
      #pragma unroll
      for (int nt = 0; nt < 4; ++nt)
        acc[mt][nt] = __builtin_amdgcn_mfma_f32_16x16x32_bf16(a[mt], b[nt], acc[mt][nt], 0, 0, 0);
  }

  if (EPI == 0){
    unsigned short* qkv = (unsigned short*)outp;
    #pragma unroll
    for (int nt = 0; nt < 4; ++nt){
      const int n = n0 + wc * 64 + nt * 16 + l15;
      const int which = n / 768;
      const int h = (n - which * 768) >> 6;
      const int hd = n & 63;
      const float bs = bias[n];
      #pragma unroll
      for (int mt = 0; mt < 4; ++mt)
        #pragma unroll
        for (int r = 0; r < 4; ++r){
          const int m = m0 + wr * 64 + mt * 16 + 4 * g + r;
          const int bb = m >> 11, s = m & 2047;
          qkv[(size_t)which * 6291456u +
              ((((size_t)bb * 12 + h) * 2048 + s) * 64 + hd)] = f2bf(acc[mt][nt][r] + bs);
        }
    }
  } else {
    float* out = (float*)outp;
    #pragma unroll
    for (int mt = 0; mt < 4; ++mt)
      #pragma unroll
      for (int nt = 0; nt < 4; ++nt){
        const int n = n0 + wc * 64 + nt * 16 + l15;
        const float bs = bias[n];
        #pragma unroll
        for (int r = 0; r < 4; ++r){
          const int m = m0 + wr * 64 + mt * 16 + 4 * g + r;
          out[(size_t)m * 768 + n] = acc[mt][nt][r] + bs;
        }
      }
  }
}

// ---------------- flash attention: q/k/v [BH=48][S=2048][64] bf16 ----------------
__global__ __launch_bounds__(256) void attn_fwd(const unsigned short* __restrict__ qw,
                                                const unsigned short* __restrict__ kw,
                                                const unsigned short* __restrict__ vw,
                                                unsigned short* __restrict__ aout){
  __shared__ unsigned short Ks[2][64 * 64];   // [key][hd], swizzled content
  __shared__ unsigned short Vt[64 * 72];      // [hd][key], padded
  __shared__ unsigned short Pl[128 * 72];     // [qrow][key], padded
  const int tid = threadIdx.x;
  const int wave = tid >> 6, lane = tid & 63;
  const int g = lane >> 4, l15 = lane & 15;
  const int bh = blockIdx.y;
  const int q0 = blockIdx.x * 128;
  const size_t base = (size_t)bh * 2048 * 64;
  const int srow = wave * 32;

  short8 qf[2][2];
  #pragma unroll
  for (int mt = 0; mt < 2; ++mt)
    #pragma unroll
    for (int ks = 0; ks < 2; ++ks)
      qf[mt][ks] = *(const short8*)(qw + base + (size_t)(q0 + srow + mt * 16 + l15) * 64 + ks * 32 + g * 8);

  f32x4 acc[2][4] = {};
  float mrow[2][4], lrow[2][4];
  #pragma unroll
  for (int mt = 0; mt < 2; ++mt)
    #pragma unroll
    for (int r = 0; r < 4; ++r){ mrow[mt][r] = -1e30f; lrow[mt][r] = 0.f; }

  uint4 vreg[2];

  auto stageK = [&](int bi, int t){
    const int kv0 = t * 64;
    #pragma unroll
    for (int c = 0; c < 2; ++c){
      const int z = c * 4096 + tid * 16;
      const int r = z >> 7, y = z & 127;
      gload_lds16((const char*)kw + (base + (size_t)(kv0 + r) * 64) * 2 + (y ^ ((r & 7) << 4)),
                  (char*)&Ks[bi][0] + c * 4096 + wave * 1024);
    }
  };
  auto vload = [&](int t){
    const int kv0 = t * 64;
    #pragma unroll
    for (int c = 0; c < 2; ++c){
      const int chunk = tid + c * 256;
      vreg[c] = *(const uint4*)(vw + base + (size_t)(kv0 + (chunk >> 3)) * 64 + (chunk & 7) * 8);
    }
  };
  auto vwrite = [&](){
    #pragma unroll
    for (int c = 0; c < 2; ++c){
      const int chunk = tid + c * 256;
      const int key = chunk >> 3, hd0 = (chunk & 7) * 8;
      const unsigned short* e = (const unsigned short*)&vreg[c];
      #pragma unroll
      for (int j = 0; j < 8; ++j)
        Vt[(hd0 + j) * 72 + key] = e[j];
    }
  };

  stageK(0, 0); vload(0); vwrite();
  __syncthreads();
  int buf = 0;
  for (int t = 0; t < 32; ++t){
    if (t + 1 < 32){ stageK(buf ^ 1, t + 1); vload(t + 1); }

    // S = Q K^T
    f32x4 s[2][4] = {};
    #pragma unroll
    for (int ct = 0; ct < 4; ++ct)
      #pragma unroll
      for (int ks = 0; ks < 2; ++ks){
        const int row = ct * 16 + l15;
        short8 kf = *(const short8*)((const char*)&Ks[buf][0] + row * 128 +
                                     ((ks * 64 + g * 16) ^ ((row & 7) << 4)));
        #pragma unroll
        for (int mt = 0; mt < 2; ++mt)
          s[mt][ct] = __builtin_amdgcn_mfma_f32_16x16x32_bf16(qf[mt][ks], kf, s[mt][ct], 0, 0, 0);
      }

    // online softmax (scale 1/sqrt(64) = 0.125)
    #pragma unroll
    for (int mt = 0; mt < 2; ++mt)
      #pragma unroll
      for (int r = 0; r < 4; ++r){
        float tm = fmaxf(fmaxf(s[mt][0][r], s[mt][1][r]), fmaxf(s[mt][2][r], s[mt][3][r])) * 0.125f;
        #pragma unroll
        for (int msk = 1; msk < 16; msk <<= 1) tm = fmaxf(tm, __shfl_xor(tm, msk));
        const float mn = fmaxf(mrow[mt][r], tm);
        const float fr = __expf(mrow[mt][r] - mn);
        mrow[mt][r] = mn;
        float rs = 0.f;
        #pragma unroll
        for (int ct = 0; ct < 4; ++ct){
          const float p = __expf(s[mt][ct][r] * 0.125f - mn);
          s[mt][ct][r] = p;
          rs += p;
        }
        #pragma unroll
        for (int msk = 1; msk < 16; msk <<= 1) rs += __shfl_xor(rs, msk);
        lrow[mt][r] = lrow[mt][r] * fr + rs;
        #pragma unroll
        for (int ht = 0; ht < 4; ++ht) acc[mt][ht][r] *= fr;
      }

    // P -> LDS (bf16)
    #pragma unroll
    for (int mt = 0; mt < 2; ++mt)
      #pragma unroll
      for (int ct = 0; ct < 4; ++ct)
        #pragma unroll
        for (int r = 0; r < 4; ++r)
          Pl[(srow + mt * 16 + 4 * g + r) * 72 + ct * 16 + l15] = f2bf(s[mt][ct][r]);

    // O += P V
    #pragma unroll
    for (int ks = 0; ks < 2; ++ks){
      short8 pa[2];
      #pragma unroll
      for (int mt = 0; mt < 2; ++mt)
        pa[mt] = *(const short8*)((const char*)&Pl[0] + (srow + mt * 16 + l15) * 144 + ks * 64 + g * 16);
      #pragma unroll
      for (int ht = 0; ht < 4; ++ht){
        short8 vb = *(const short8*)((const char*)&Vt[0] + (ht * 16 + l15) * 144 + ks * 64 + g * 16);
        #pragma unroll
        for (int mt = 0; mt < 2; ++mt)
          acc[mt][ht] = __builtin_amdgcn_mfma_f32_16x16x32_bf16(pa[mt], vb, acc[mt][ht], 0, 0, 0);
      }
    }

    __syncthreads();
    if (t + 1 < 32) vwrite();
    __syncthreads();
    buf ^= 1;
  }

  const int bb = bh / 12, h = bh % 12;
  #pragma unroll
  for (int mt = 0; mt < 2; ++mt)
    #pragma unroll
    for (int ht = 0; ht < 4; ++ht)
      #pragma unroll
      for (int r = 0; r < 4; ++r){
        const int row = q0 + srow + mt * 16 + 4 * g + r;
        aout[(size_t)(bb * 2048 + row) * 768 + h * 64 + ht * 16 + l15] =
            f2bf(acc[mt][ht][r] / lrow[mt][r]);
      }
}

extern "C" void kernel_launch(void* const* d_in, const int* in_sizes, int n_in,
                              void* d_out, int out_size, void* d_ws, size_t ws_size,
                              hipStream_t stream){
  const float* hs = (const float*)d_in[0];
  const float* Wa = (const float*)d_in[1];
  const float* ba = (const float*)d_in[2];
  const float* Wp = (const float*)d_in[3];
  const float* bp = (const float*)d_in[4];

  char* ws = (char*)d_ws;
  unsigned short* hbf = (unsigned short*)ws;                                    // 8192x768 bf16
  unsigned short* WaT = (unsigned short*)(ws + 12582912);                       // 2304x768 bf16
  unsigned short* WpT = (unsigned short*)(ws + 12582912 + 3538944);             // 768x768 bf16
  unsigned short* qkv = (unsigned short*)(ws + 12582912 + 3538944 + 1179648);   // 3 x [48][2048][64]
  unsigned short* abf = qkv + (size_t)3 * 6291456;                              // 8192x768 bf16

  cast_f32_bf16<<<dim3(2048), dim3(256), 0, stream>>>(hs, hbf, 8192 * 768 / 4);
  transpose_to_bf16<<<dim3(36, 12), dim3(256), 0, stream>>>(Wa, WaT, 768, 2304);
  transpose_to_bf16<<<dim3(12, 12), dim3(256), 0, stream>>>(Wp, WpT, 768, 768);
  gemm_bf16<0><<<dim3(18, 64), dim3(256), 0, stream>>>(hbf, WaT, ba, (void*)qkv);
  attn_fwd<<<dim3(16, 48), dim3(256), 0, stream>>>(qkv, qkv + 6291456, qkv + (size_t)2 * 6291456, abf);
  gemm_bf16<1><<<dim3(6, 64), dim3(256), 0, stream>>>(abf, WpT, bp, d_out);
}

// Round 2
// 187.520 us; speedup vs baseline: 1.7398x; 1.7398x over previous
//
#include <hip/hip_runtime.h>

typedef short short8 __attribute__((ext_vector_type(8)));
typedef float f32x4 __attribute__((ext_vector_type(4)));
typedef float f32x16 __attribute__((ext_vector_type(16)));

__device__ __forceinline__ unsigned short f2bf(float f){
  union { float f; unsigned int u; } x; x.f = f;
  unsigned int r = x.u + 0x7fffu + ((x.u >> 16) & 1u);
  return (unsigned short)(r >> 16);
}

__device__ __forceinline__ void gload_lds16(const void* g, void* l){
  __builtin_amdgcn_global_load_lds(
      (const __attribute__((address_space(1))) void*)g,
      (__attribute__((address_space(3))) void*)l, 16, 0, 0);
}

__device__ __forceinline__ unsigned int cvtpk_bf16(float lo, float hi){
  unsigned int r;
  asm("v_cvt_pk_bf16_f32 %0, %1, %2" : "=v"(r) : "v"(lo), "v"(hi));
  return r;
}

// ---------------- cast fp32 -> bf16 ----------------
__global__ __launch_bounds__(256) void cast_f32_bf16(const float* __restrict__ in,
                                                     unsigned short* __restrict__ out, int n4){
  int i = blockIdx.x * blockDim.x + threadIdx.x;
  const int stride = gridDim.x * blockDim.x;
  for (; i < n4; i += stride){
    float4 v = ((const float4*)in)[i];
    ushort4 o;
    o.x = f2bf(v.x); o.y = f2bf(v.y); o.z = f2bf(v.z); o.w = f2bf(v.w);
    ((ushort4*)out)[i] = o;
  }
}

// ---------------- transpose W[K][N] f32 -> WT[N][K] bf16 ----------------
__global__ __launch_bounds__(256) void transpose_to_bf16(const float* __restrict__ W,
                                                         unsigned short* __restrict__ WT,
                                                         int K, int N){
  __shared__ float tile[64][68];
  const int n0 = blockIdx.x * 64, k0 = blockIdx.y * 64;
  const int t = threadIdx.x;
  const int qn = (t & 15) * 4;
  #pragma unroll
  for (int i = 0; i < 4; ++i){
    const int kk = (t >> 4) + i * 16;
    float4 v = *(const float4*)&W[(size_t)(k0 + kk) * N + n0 + qn];
    tile[kk][qn + 0] = v.x; tile[kk][qn + 1] = v.y;
    tile[kk][qn + 2] = v.z; tile[kk][qn + 3] = v.w;
  }
  __syncthreads();
  const int qk = (t & 15) * 4;
  #pragma unroll
  for (int i = 0; i < 4; ++i){
    const int nn = (t >> 4) + i * 16;
    ushort4 o;
    o.x = f2bf(tile[qk + 0][nn]); o.y = f2bf(tile[qk + 1][nn]);
    o.z = f2bf(tile[qk + 2][nn]); o.w = f2bf(tile[qk + 3][nn]);
    *(ushort4*)&WT[(size_t)(n0 + nn) * K + k0 + qk] = o;
  }
}

// ---------------- GEMM: A[8192][768]bf16 x Bt[N][768]bf16 ----------------
// EPI 0: scatter q (scaled 0.125) / k to [bh][s][64], v TRANSPOSED to [bh][hd][2048]
// EPI 1: out fp32 [8192][768] + bias
template<int EPI>
__global__ __launch_bounds__(256) void gemm_bf16(const unsigned short* __restrict__ A,
                                                 const unsigned short* __restrict__ Bt,
                                                 const float* __restrict__ bias,
                                                 void* __restrict__ outp){
  __shared__ unsigned short As[2][128 * 32];
  __shared__ unsigned short Bs[2][128 * 32];
  const int tid = threadIdx.x;
  const int wave = tid >> 6, lane = tid & 63;
  const int g = lane >> 4, l15 = lane & 15;
  const int wr = wave >> 1, wc = wave & 1;
  const int m0 = blockIdx.y * 128, n0 = blockIdx.x * 128;

  f32x4 acc[4][4] = {};

  auto stage = [&](int bi, int kt){
    const int k0 = kt * 32;
    #pragma unroll
    for (int c = 0; c < 2; ++c){
      const int z = c * 4096 + tid * 16;
      const int r = z >> 6;
      const int ys = (z & 63) ^ ((r & 3) << 4);
      gload_lds16((const char*)A + ((size_t)(m0 + r) * 768 + k0) * 2 + ys,
                  (char*)&As[bi][0] + c * 4096 + wave * 1024);
      gload_lds16((const char*)Bt + ((size_t)(n0 + r) * 768 + k0) * 2 + ys,
                  (char*)&Bs[bi][0] + c * 4096 + wave * 1024);
    }
  };

  stage(0, 0);
  for (int kt = 0; kt < 24; ++kt){
    __syncthreads();
    if (kt + 1 < 24) stage((kt + 1) & 1, kt + 1);
    const char* Ab = (const char*)&As[kt & 1][0];
    const char* Bb = (const char*)&Bs[kt & 1][0];
    short8 a[4], b[4];
    #pragma unroll
    for (int mt = 0; mt < 4; ++mt){
      const int row = wr * 64 + mt * 16 + l15;
      a[mt] = *(const short8*)(Ab + row * 64 + ((g * 16) ^ ((row & 3) << 4)));
    }
    #pragma unroll
    for (int nt = 0; nt < 4; ++nt){
      const int row = wc * 64 + nt * 16 + l15;
      b[nt] = *(const short8*)(Bb + row * 64 + ((g * 16) ^ ((row & 3) << 4)));
    }
    #pragma unroll
    for (int mt = 0; mt < 4; ++mt)
      #pragma unroll
      for (int nt = 0; nt < 4; ++nt)
        acc[mt][nt] = __builtin_amdgcn_mfma_f32_16x16x32_bf16(a[mt], b[nt], acc[mt][nt], 0, 0, 0);
  }

  if (EPI == 0){
    unsigned short* qkv = (unsigned short*)outp;
    #pragma unroll
    for (int nt = 0; nt < 4; ++nt){
      const int n = n0 + wc * 64 + nt * 16 + l15;
      const int which = n / 768;
      const float bs = bias[n];
      if (which == 2){
        const int hd = n & 63;
        const int head = (n - 1536) >> 6;
        #pragma unroll
        for (int mt = 0; mt < 4; ++mt){
          const int m = m0 + wr * 64 + mt * 16 + 4 * g;
          const int bb = m >> 11, sidx = m & 2047;
          unsigned short* dst = qkv + (size_t)2 * 6291456 +
                                ((size_t)(bb * 12 + head) * 64 + hd) * 2048 + sidx;
          #pragma unroll
          for (int rp = 0; rp < 2; ++rp){
            const unsigned int lo = f2bf(acc[mt][nt][2 * rp] + bs);
            const unsigned int hi = f2bf(acc[mt][nt][2 * rp + 1] + bs);
            *(unsigned int*)(dst + 2 * rp) = lo | (hi << 16);
          }
        }
      } else {
        const int h2 = (n - which * 768) >> 6;
        const int hd = n & 63;
        const float sc = (which == 0) ? 0.125f : 1.0f;
        #pragma unroll
        for (int mt = 0; mt < 4; ++mt)
          #pragma unroll
          for (int r = 0; r < 4; ++r){
            const int m = m0 + wr * 64 + mt * 16 + 4 * g + r;
            const int bb = m >> 11, sidx = m & 2047;
            qkv[(size_t)which * 6291456u +
                ((((size_t)bb * 12 + h2) * 2048 + sidx) * 64 + hd)] = f2bf((acc[mt][nt][r] + bs) * sc);
          }
      }
    }
  } else {
    float* out = (float*)outp;
    #pragma unroll
    for (int mt = 0; mt < 4; ++mt)
      #pragma unroll
      for (int nt = 0; nt < 4; ++nt){
        const int n = n0 + wc * 64 + nt * 16 + l15;
        const float bs = bias[n];
        #pragma unroll
        for (int r = 0; r < 4; ++r){
          const int m = m0 + wr * 64 + mt * 16 + 4 * g + r;
          out[(size_t)m * 768 + n] = acc[mt][nt][r] + bs;
        }
      }
  }
}

// ---------------- flash attention, swapped-QK^T 32x32 structure ----------------
// q,k: [bh][s][64] bf16 (q pre-scaled by 0.125); vT: [bh][hd=64][s=2048] bf16
__global__ __launch_bounds__(256) void attn_fwd2(const unsigned short* __restrict__ qw,
                                                 const unsigned short* __restrict__ kw,
                                                 const unsigned short* __restrict__ vtw,
                                                 unsigned short* __restrict__ aout){
  __shared__ unsigned short Ks[2][64 * 64];   // [key][hd], byte-col ^ ((key&7)<<4)
  __shared__ unsigned short Vs[2][64 * 64];   // [hd][key], byte-col ^ ((hd&7)<<4)
  __shared__ float bcast[4][32];
  const int tid = threadIdx.x;
  const int wave = tid >> 6, lane = tid & 63;
  const int h = lane >> 5, ql = lane & 31;
  const int bh = blockIdx.y;
  const int q0 = blockIdx.x * 128 + wave * 32;
  const size_t base = (size_t)bh * 2048 * 64;

  // Q fragments (B-operand): lane holds Q[q0+ql][c*16 + h*8 .. +7]
  short8 qf[4];
  #pragma unroll
  for (int c = 0; c < 4; ++c)
    qf[c] = *(const short8*)(qw + base + (size_t)(q0 + ql) * 64 + c * 16 + h * 8);

  f32x16 acc[2] = {};
  float mreg = -1e30f, lsum = 0.f;

  auto stageKV = [&](int bi, int t){
    #pragma unroll
    for (int c = 0; c < 2; ++c){
      const int z = c * 4096 + tid * 16;
      const int r = z >> 7, y = z & 127;
      const int ys = y ^ ((r & 7) << 4);
      gload_lds16((const char*)kw + (base + (size_t)(t * 64 + r) * 64) * 2 + ys,
                  (char*)&Ks[bi][0] + z);
      gload_lds16((const char*)vtw + (base + (size_t)r * 2048 + t * 64) * 2 + ys,
                  (char*)&Vs[bi][0] + z);
    }
  };

  stageKV(0, 0);
  __syncthreads();

  for (int t = 0; t < 32; ++t){
    const int buf = t & 1;
    if (t + 1 < 32) stageKV(buf ^ 1, t + 1);

    // S^T = K Q^T : per kt (32 keys), accumulate over 4 hd-chunks
    f32x16 s[2] = {};
    #pragma unroll
    for (int kt = 0; kt < 2; ++kt)
      #pragma unroll
      for (int c = 0; c < 4; ++c){
        const int row = kt * 32 + ql;
        short8 af = *(const short8*)((const char*)&Ks[buf][0] + row * 128 +
                                     ((c * 32 + h * 16) ^ ((row & 7) << 4)));
        s[kt] = __builtin_amdgcn_mfma_f32_32x32x16_bf16(af, qf[c], s[kt], 0, 0, 0);
      }

    // online softmax: lane owns q=ql, 32 of its 64 keys (other half in lane^32)
    float pm = s[0][0];
    #pragma unroll
    for (int kt = 0; kt < 2; ++kt)
      #pragma unroll
      for (int r = 0; r < 16; ++r) pm = fmaxf(pm, s[kt][r]);
    pm = fmaxf(pm, __shfl_xor(pm, 32));

    if (__any(pm > mreg + 8.f)){
      const float mn = fmaxf(mreg, pm);
      const float fr = __expf(mreg - mn);
      mreg = mn;
      lsum *= fr;
      if (h == 0) bcast[wave][ql] = fr;
      #pragma unroll
      for (int g4 = 0; g4 < 4; ++g4){
        float4 f4 = *(const float4*)&bcast[wave][8 * g4 + 4 * h];
        #pragma unroll
        for (int j = 0; j < 4; ++j){
          const float fj = ((const float*)&f4)[j];
          acc[0][4 * g4 + j] *= fj;
          acc[1][4 * g4 + j] *= fj;
        }
      }
    }

    float ps = 0.f;
    #pragma unroll
    for (int kt = 0; kt < 2; ++kt)
      #pragma unroll
      for (int r = 0; r < 16; ++r){
        const float p = __expf(s[kt][r] - mreg);
        s[kt][r] = p;
        ps += p;
      }
    lsum += ps;

    // O += P V : build A-frags in-register (cvt_pk + permlane32_swap)
    #pragma unroll
    for (int kt = 0; kt < 2; ++kt){
      unsigned int w0 = cvtpk_bf16(s[kt][0],  s[kt][1]),  x0 = cvtpk_bf16(s[kt][4],  s[kt][5]);
      asm("v_permlane32_swap_b32 %0, %1" : "+v"(w0), "+v"(x0));
      unsigned int w1 = cvtpk_bf16(s[kt][2],  s[kt][3]),  x1 = cvtpk_bf16(s[kt][6],  s[kt][7]);
      asm("v_permlane32_swap_b32 %0, %1" : "+v"(w1), "+v"(x1));
      unsigned int w2 = cvtpk_bf16(s[kt][8],  s[kt][9]),  x2 = cvtpk_bf16(s[kt][12], s[kt][13]);
      asm("v_permlane32_swap_b32 %0, %1" : "+v"(w2), "+v"(x2));
      unsigned int w3 = cvtpk_bf16(s[kt][10], s[kt][11]), x3 = cvtpk_bf16(s[kt][14], s[kt][15]);
      asm("v_permlane32_swap_b32 %0, %1" : "+v"(w3), "+v"(x3));
      union { unsigned int u[4]; short8 v; } pa[2];
      pa[0].u[0] = w0; pa[0].u[1] = w1; pa[0].u[2] = x0; pa[0].u[3] = x1;
      pa[1].u[0] = w2; pa[1].u[1] = w3; pa[1].u[2] = x2; pa[1].u[3] = x3;
      #pragma unroll
      for (int c2 = 0; c2 < 2; ++c2){
        const int kc = kt * 2 + c2;
        #pragma unroll
        for (int ht = 0; ht < 2; ++ht){
          const int row = ht * 32 + ql;
          short8 vb = *(const short8*)((const char*)&Vs[buf][0] + row * 128 +
                                       ((kc * 32 + h * 16) ^ ((row & 7) << 4)));
          acc[ht] = __builtin_amdgcn_mfma_f32_32x32x16_bf16(pa[c2].v, vb, acc[ht], 0, 0, 0);
        }
      }
    }

    __syncthreads();
  }

  // epilogue: combine halves of l, broadcast 1/l per row, write out
  lsum += __shfl_xor(lsum, 32);
  if (h == 0) bcast[wave][ql] = 1.0f / lsum;
  const int bb = bh / 12, hh = bh % 12;
  #pragma unroll
  for (int g4 = 0; g4 < 4; ++g4){
    float4 f4 = *(const float4*)&bcast[wave][8 * g4 + 4 * h];
    #pragma unroll
    for (int j = 0; j < 4; ++j){
      const int row = 8 * g4 + 4 * h + j;
      const float li = ((const float*)&f4)[j];
      #pragma unroll
      for (int ht = 0; ht < 2; ++ht)
        aout[(size_t)(bb * 2048 + q0 + row) * 768 + hh * 64 + ht * 32 + ql] =
            f2bf(acc[ht][4 * g4 + j] * li);
    }
  }
}

extern "C" void kernel_launch(void* const* d_in, const int* in_sizes, int n_in,
                              void* d_out, int out_size, void* d_ws, size_t ws_size,
                              hipStream_t stream){
  const float* hs = (const float*)d_in[0];
  const float* Wa = (const float*)d_in[1];
  const float* ba = (const float*)d_in[2];
  const float* Wp = (const float*)d_in[3];
  const float* bp = (const float*)d_in[4];

  char* ws = (char*)d_ws;
  unsigned short* hbf = (unsigned short*)ws;                                    // 8192x768 bf16
  unsigned short* WaT = (unsigned short*)(ws + 12582912);                       // 2304x768 bf16
  unsigned short* WpT = (unsigned short*)(ws + 12582912 + 3538944);             // 768x768 bf16
  unsigned short* qkv = (unsigned short*)(ws + 12582912 + 3538944 + 1179648);   // q,k: [48][2048][64]; vT: [48][64][2048]
  unsigned short* abf = qkv + (size_t)3 * 6291456;                              // 8192x768 bf16

  cast_f32_bf16<<<dim3(2048), dim3(256), 0, stream>>>(hs, hbf, 8192 * 768 / 4);
  transpose_to_bf16<<<dim3(36, 12), dim3(256), 0, stream>>>(Wa, WaT, 768, 2304);
  transpose_to_bf16<<<dim3(12, 12), dim3(256), 0, stream>>>(Wp, WpT, 768, 768);
  gemm_bf16<0><<<dim3(18, 64), dim3(256), 0, stream>>>(hbf, WaT, ba, (void*)qkv);
  attn_fwd2<<<dim3(16, 48), dim3(256), 0, stream>>>(qkv, qkv + 6291456, qkv + (size_t)2 * 6291456, abf);
  gemm_bf16<1><<<dim3(6, 64), dim3(256), 0, stream>>>(abf, WpT, bp, d_out);
}